// Round 1
// baseline (484.252 us; speedup 1.0000x reference)
//
#include <hip/hip_runtime.h>
#include <stdint.h>

// Problem constants: B=4, NP=512, NC=256, E=128, C=32, NBUCKET=20.

typedef float f32x4 __attribute__((ext_vector_type(4)));
typedef short s16x8 __attribute__((ext_vector_type(8)));

#define DEV static __device__ __forceinline__

DEV unsigned short f2bf(float f) {
  unsigned u = __builtin_bit_cast(unsigned, f);
  u += 0x7FFFu + ((u >> 16) & 1u);   // RNE
  return (unsigned short)(u >> 16);
}
DEV float bf2f(unsigned short h) {
  unsigned u = ((unsigned)h) << 16;
  return __builtin_bit_cast(float, u);
}

// ---------------------------------------------------------------- prep ----
// ws transposed-weight staging: WTO[e][k]=W_out[k][e] (bf16), PT[b][e][np]=
// pocket[b][np][e] (bf16), WT_LIN[c][k]=W_lin[k][c] (bf16), ACC zeroed.
__global__ void prep_k(const float* __restrict__ wlin,
                       const float* __restrict__ pocket,
                       const float* __restrict__ wout,
                       unsigned short* __restrict__ wtlin,
                       unsigned short* __restrict__ pt,
                       unsigned short* __restrict__ wto,
                       float* __restrict__ accg) {
  for (int i = blockIdx.x * 256 + threadIdx.x; i < 790536; i += gridDim.x * 256) {
    if (i < 524288) {                 // WTO: 128 e x 4096 k
      int e = i >> 12, k = i & 4095;
      wto[i] = f2bf(wout[k * 128 + e]);
    } else if (i < 786432) {          // PT: [b][e][np]
      int i2 = i - 524288;
      int np = i2 & 511, r = i2 >> 9;
      int e = r & 127, b = r >> 7;
      pt[i2] = f2bf(pocket[(b * 512 + np) * 128 + e]);
    } else if (i < 790528) {          // WT_LIN: [c][k]
      int i3 = i - 786432;
      int k = i3 & 127, c = i3 >> 7;
      wtlin[i3] = f2bf(wlin[k * 32 + c]);
    } else {
      accg[i - 790528] = 0.0f;        // 8 accumulators (aff[4], prmsd[4])
    }
  }
}

// ---------------------------------------------------------------- mega ----
// One block per (nc, b). Phases:
//  1. zc_pre = z @ W_lin via bf16 MFMA (LDS-staged z, fp32 accum). b_lin is
//     skipped: constant per softmax row -> cancels in softmax.
//  2. softmax over np (fp32, cross-lane + LDS reduction), store T bf16 [32][520].
//  3. dis_bias on the fly (scrambled reshape), + scrambled mask -> T final.
//  4. gated energy heads (fp32) -> atomicAdd into ACC.
//  5. einsum lig[c,e] = sum_np T[c,np]*P[np,e] via MFMA -> LIG bf16.
extern __shared__ char smem[];  // 57856 B: zbuf fp32[256][36] overlaid by
                                // T u16[32][520] (33280 B) + ubuf u16[512][24]

__global__ __launch_bounds__(256, 2) void mega_k(
    const float* __restrict__ z, const int* __restrict__ zmask,
    const float* __restrict__ cdis,
    const float* __restrict__ wdis, const float* __restrict__ bdis_g,
    const float* __restrict__ wE, const float* __restrict__ bE,
    const float* __restrict__ wG, const float* __restrict__ bG,
    const float* __restrict__ wEp, const float* __restrict__ bEp,
    const float* __restrict__ wGp, const float* __restrict__ bGp,
    const unsigned short* __restrict__ wtlin,
    const unsigned short* __restrict__ pt,
    unsigned short* __restrict__ lig, float* __restrict__ accg) {
  const int nc = blockIdx.x, b = blockIdx.y;
  const int t = threadIdx.x;
  const int w = t >> 6, ln = t & 63;
  const int m16 = ln & 15, q = ln >> 4;

  float* zbuf = (float*)smem;                              // [256][36]
  unsigned short* T = (unsigned short*)smem;               // [32][520]
  unsigned short* ub = (unsigned short*)(smem + 33280);    // [512][24]

  __shared__ float s_wd[640];                              // W_dis [20][32]
  __shared__ float s_bd[32];
  __shared__ float s_we[32], s_wg[32], s_wep[32], s_wgp[32];
  __shared__ float s_red[160];                             // [32][5]
  __shared__ float s_gmax[32], s_gsum[32];
  __shared__ unsigned long long s_mb[4][8];                // mask bits
  __shared__ float s_r8[8];

  if (t < 32) {
    s_bd[t] = bdis_g[t];
    s_we[t] = wE[t]; s_wg[t] = wG[t];
    s_wep[t] = wEp[t]; s_wgp[t] = wGp[t];
  }
  for (int i = t; i < 640; i += 256) s_wd[i] = wdis[i];
  // mask_rep[b,c,nc,np] = z_mask[c&3][2nc+np/256][np&255]; for fixed nc the
  // needed values are contiguous: zmask[cm*131072 + nc*512 + nn], nn=np.
  for (int i = t; i < 2048; i += 256) {
    int cm = i >> 9, nn = i & 511;
    unsigned long long bal = __ballot(zmask[cm * 131072 + nc * 512 + nn] != 0);
    if ((i & 63) == 0) s_mb[cm][nn >> 6] = bal;
  }

  // ---- Phase 1: MFMA GEMM. wave w owns np tiles: np0 = 256h + (4w+i)*16.
  f32x4 acc1[8][2];
#pragma unroll
  for (int i = 0; i < 8; ++i) {
    acc1[i][0] = f32x4{0.f, 0.f, 0.f, 0.f};
    acc1[i][1] = f32x4{0.f, 0.f, 0.f, 0.f};
  }
  const int zb0 = b * 16777216 + nc * 128;
  for (int k0 = 0; k0 < 128; k0 += 32) {
    // B-frags: BT rows = WT_LIN[c][k-run 8] (L1-resident)
    s16x8 bf0 = *(const s16x8*)(wtlin + m16 * 128 + k0 + q * 8);
    s16x8 bf1 = *(const s16x8*)(wtlin + (16 + m16) * 128 + k0 + q * 8);
    for (int h = 0; h < 2; ++h) {
      __syncthreads();
      // stage 256 np-rows x 32 k fp32, coalesced (8 float4/thread)
#pragma unroll
      for (int jj = 0; jj < 8; ++jj) {
        int f = jj * 256 + t;
        int row = f >> 3, qq = f & 7;
        f32x4 v = *(const f32x4*)(z + zb0 + (h * 256 + row) * 32768 + k0 + qq * 4);
        *(f32x4*)(zbuf + row * 36 + qq * 4) = v;
      }
      __syncthreads();
#pragma unroll
      for (int i = 0; i < 4; ++i) {
        int lrow = (w * 4 + i) * 16 + m16;   // A[m=lane&15][k=q*8+j]
        f32x4 z0 = *(const f32x4*)(zbuf + lrow * 36 + q * 8);
        f32x4 z1 = *(const f32x4*)(zbuf + lrow * 36 + q * 8 + 4);
        s16x8 af;
        af[0] = (short)f2bf(z0[0]); af[1] = (short)f2bf(z0[1]);
        af[2] = (short)f2bf(z0[2]); af[3] = (short)f2bf(z0[3]);
        af[4] = (short)f2bf(z1[0]); af[5] = (short)f2bf(z1[1]);
        af[6] = (short)f2bf(z1[2]); af[7] = (short)f2bf(z1[3]);
        int ai = h * 4 + i;
        acc1[ai][0] = __builtin_amdgcn_mfma_f32_16x16x32_bf16(af, bf0, acc1[ai][0], 0, 0, 0);
        acc1[ai][1] = __builtin_amdgcn_mfma_f32_16x16x32_bf16(af, bf1, acc1[ai][1], 0, 0, 0);
      }
    }
  }

  // ---- Phase 2: softmax over np per c. D-frag: col(c)=ln&15, row(np)=q*4+r.
  float mx[2] = {-3.0e38f, -3.0e38f};
#pragma unroll
  for (int ai = 0; ai < 8; ++ai)
#pragma unroll
    for (int ct = 0; ct < 2; ++ct)
#pragma unroll
      for (int r = 0; r < 4; ++r) mx[ct] = fmaxf(mx[ct], acc1[ai][ct][r]);
#pragma unroll
  for (int ct = 0; ct < 2; ++ct) {
    float v = mx[ct];
    v = fmaxf(v, __shfl_xor(v, 16));
    v = fmaxf(v, __shfl_xor(v, 32));
    mx[ct] = v;
  }
  if (ln < 16) { s_red[ln * 5 + w] = mx[0]; s_red[(16 + ln) * 5 + w] = mx[1]; }
  __syncthreads();
  if (t < 32)
    s_gmax[t] = fmaxf(fmaxf(s_red[t * 5], s_red[t * 5 + 1]),
                      fmaxf(s_red[t * 5 + 2], s_red[t * 5 + 3]));
  __syncthreads();
  float sm[2] = {0.f, 0.f};
#pragma unroll
  for (int ct = 0; ct < 2; ++ct) {
    float g = s_gmax[ct * 16 + m16];
#pragma unroll
    for (int ai = 0; ai < 8; ++ai)
#pragma unroll
      for (int r = 0; r < 4; ++r) {
        float e = __expf(acc1[ai][ct][r] - g);
        acc1[ai][ct][r] = e;
        sm[ct] += e;
      }
  }
#pragma unroll
  for (int ct = 0; ct < 2; ++ct) {
    float v = sm[ct];
    v += __shfl_xor(v, 16);
    v += __shfl_xor(v, 32);
    sm[ct] = v;
  }
  if (ln < 16) { s_red[ln * 5 + w] = sm[0]; s_red[(16 + ln) * 5 + w] = sm[1]; }
  __syncthreads();
  if (t < 32)
    s_gsum[t] = 1.0f / (s_red[t * 5] + s_red[t * 5 + 1] + s_red[t * 5 + 2] + s_red[t * 5 + 3]);
  __syncthreads();

  // ---- Phase 2b: scale + store T bf16 (zbuf is dead; T overlays it)
#pragma unroll
  for (int ct = 0; ct < 2; ++ct) {
    int c = ct * 16 + m16;
    float s = s_gsum[c];
#pragma unroll
    for (int ai = 0; ai < 8; ++ai) {
      int npb = (ai >> 2) * 256 + (w * 4 + (ai & 3)) * 16 + q * 4;
#pragma unroll
      for (int r = 0; r < 4; ++r) T[c * 520 + npb + r] = f2bf(acc1[ai][ct][r] * s);
    }
  }

  // ---- Phase 3a: bucket values u for 512 tasks (c,np5) x 20 buckets.
  // dis_bias[b,c,nc,np] = D[b, p=16c+nc/16, cc=16(nc&15)+np/32, k=np&31]
  {
    const float SUSK = 1.14136f * __expf(2.0f);
    const int nc4 = nc >> 4, nc15 = nc & 15;
    for (int it = 0; it < 40; ++it) {
      int vid = it * 256 + t;
      int task = vid / 20, j = vid - task * 20;
      int c = task & 31, np5 = task >> 5;
      int p = 16 * c + nc4, cc = 16 * nc15 + np5;
      float d = cdis[(b * 512 + p) * 256 + cc];
      float diff = d * (21.0f / 15.0f) - (float)(j + 1);
      float y1 = diff + 1.f, y2 = 1.f - diff;
      float u = 0.f;
      if (y1 > 0.f && y2 > 0.f) u = SUSK * __expf(-1.f / y1 - 1.f / y2);
      ub[task * 24 + j] = f2bf(u);
    }
  }
  __syncthreads();

  // ---- Phase 3b: D = U @ W_dis (K=20) + b_dis, add into T, apply mask.
  {
    const int kg = t & 3, tg = t >> 2;
    const int cB = tg & 31, np5b = tg >> 5;
    float val[8][8];
#pragma unroll
    for (int jj = 0; jj < 8; ++jj)
#pragma unroll
      for (int kk = 0; kk < 8; ++kk) val[jj][kk] = s_bd[kg * 8 + kk];
    for (int j = 0; j < 20; ++j) {
      f32x4 wd0 = *(const f32x4*)(s_wd + j * 32 + kg * 8);
      f32x4 wd1 = *(const f32x4*)(s_wd + j * 32 + kg * 8 + 4);
#pragma unroll
      for (int jj = 0; jj < 8; ++jj) {
        float u = bf2f(ub[(tg + 64 * jj) * 24 + j]);
        val[jj][0] += u * wd0[0]; val[jj][1] += u * wd0[1];
        val[jj][2] += u * wd0[2]; val[jj][3] += u * wd0[3];
        val[jj][4] += u * wd1[0]; val[jj][5] += u * wd1[1];
        val[jj][6] += u * wd1[2]; val[jj][7] += u * wd1[3];
      }
    }
    __syncthreads();  // all ubuf reads done before T RMW below races? (regions
                      // differ, but keep one barrier between 2b writes & RMW)
#pragma unroll
    for (int jj = 0; jj < 8; ++jj) {
      int np5 = np5b + 2 * jj;
      int npb = np5 * 32 + kg * 8;
      unsigned short* tp = T + cB * 520 + npb;
      s16x8 tv = *(s16x8*)tp;
      unsigned long long mw = s_mb[cB & 3][npb >> 6];
      s16x8 ov;
#pragma unroll
      for (int kk = 0; kk < 8; ++kk) {
        float x = bf2f((unsigned short)tv[kk]) + val[jj][kk];
        int mk = (int)((mw >> ((npb + kk) & 63)) & 1ull);
        ov[kk] = (short)f2bf(mk ? 1e-9f : x);
      }
      *(s16x8*)tp = ov;
    }
  }
  __syncthreads();

  // ---- Phase 4: gated energy heads; pair_energy masked by z_mask[b,np,nc]
  {
    float aff = 0.f, prm = 0.f;
    const float bg0 = bG[0], be0 = bE[0], bgp0 = bGp[0], bep0 = bEp[0];
#pragma unroll
    for (int s = 0; s < 2; ++s) {
      int np = s * 256 + t;
      float g = bg0, e = be0, gp = bgp0, ep = bep0;
      for (int c = 0; c < 32; ++c) {
        float tv = bf2f(T[c * 520 + np]);
        g += tv * s_wg[c]; e += tv * s_we[c];
        gp += tv * s_wgp[c]; ep += tv * s_wep[c];
      }
      if (zmask[(b * 512 + np) * 256 + nc] != 0) {
        aff += e / (1.f + __expf(-g));
        prm += ep / (1.f + __expf(-gp));
      }
    }
#pragma unroll
    for (int d = 32; d >= 1; d >>= 1) {
      aff += __shfl_xor(aff, d);
      prm += __shfl_xor(prm, d);
    }
    if (ln == 0) { s_r8[w] = aff; s_r8[4 + w] = prm; }
    __syncthreads();
    if (t == 0) {
      atomicAdd(accg + b, s_r8[0] + s_r8[1] + s_r8[2] + s_r8[3]);
      atomicAdd(accg + 4 + b, s_r8[4] + s_r8[5] + s_r8[6] + s_r8[7]);
    }
  }

  // ---- Phase 5: lig[c,e] = sum_np T[c,np] * P[np,e] via MFMA.
  {
    f32x4 a5[2][2];
    a5[0][0] = f32x4{0.f, 0.f, 0.f, 0.f}; a5[0][1] = a5[0][0];
    a5[1][0] = a5[0][0]; a5[1][1] = a5[0][0];
    const unsigned short* ptb = pt + b * 65536;
    for (int k0 = 0; k0 < 512; k0 += 32) {
      s16x8 aT0 = *(const s16x8*)(T + m16 * 520 + k0 + q * 8);
      s16x8 aT1 = *(const s16x8*)(T + (16 + m16) * 520 + k0 + q * 8);
      s16x8 bP0 = *(const s16x8*)(ptb + (w * 32 + m16) * 512 + k0 + q * 8);
      s16x8 bP1 = *(const s16x8*)(ptb + (w * 32 + 16 + m16) * 512 + k0 + q * 8);
      a5[0][0] = __builtin_amdgcn_mfma_f32_16x16x32_bf16(aT0, bP0, a5[0][0], 0, 0, 0);
      a5[0][1] = __builtin_amdgcn_mfma_f32_16x16x32_bf16(aT0, bP1, a5[0][1], 0, 0, 0);
      a5[1][0] = __builtin_amdgcn_mfma_f32_16x16x32_bf16(aT1, bP0, a5[1][0], 0, 0, 0);
      a5[1][1] = __builtin_amdgcn_mfma_f32_16x16x32_bf16(aT1, bP1, a5[1][1], 0, 0, 0);
    }
    unsigned short* lg = lig + (b * 256 + nc) * 4096;
#pragma unroll
    for (int mt = 0; mt < 2; ++mt)
#pragma unroll
      for (int u = 0; u < 2; ++u)
#pragma unroll
        for (int r = 0; r < 4; ++r) {
          int c = mt * 16 + q * 4 + r;
          int e = w * 32 + u * 16 + m16;
          lg[c * 128 + e] = f2bf(a5[mt][u][r]);
        }
  }
}

// ---------------------------------------------------------------- proj ----
// ligand = LIG[1024][4096] @ W_out[4096][128], split-K(16) -> fp32 partials.
__global__ __launch_bounds__(256, 2) void proj_k(
    const unsigned short* __restrict__ lig, const unsigned short* __restrict__ wto,
    float* __restrict__ part) {
  const int mb = blockIdx.x, ks = blockIdx.y;
  const int t = threadIdx.x, w = t >> 6, ln = t & 63;
  const int m16 = ln & 15, q = ln >> 4;
  f32x4 acc[2][8];
#pragma unroll
  for (int mt = 0; mt < 2; ++mt)
#pragma unroll
    for (int nt = 0; nt < 8; ++nt) acc[mt][nt] = f32x4{0.f, 0.f, 0.f, 0.f};
  const int kb = ks * 256;
  for (int k0 = 0; k0 < 256; k0 += 32) {
    s16x8 af[2], bf[8];
#pragma unroll
    for (int mt = 0; mt < 2; ++mt)
      af[mt] = *(const s16x8*)(lig + (mb * 128 + (w * 2 + mt) * 16 + m16) * 4096 + kb + k0 + q * 8);
#pragma unroll
    for (int nt = 0; nt < 8; ++nt)
      bf[nt] = *(const s16x8*)(wto + (nt * 16 + m16) * 4096 + kb + k0 + q * 8);
#pragma unroll
    for (int mt = 0; mt < 2; ++mt)
#pragma unroll
      for (int nt = 0; nt < 8; ++nt)
        acc[mt][nt] = __builtin_amdgcn_mfma_f32_16x16x32_bf16(af[mt], bf[nt], acc[mt][nt], 0, 0, 0);
  }
  float* pp = part + ks * 131072 + mb * 16384;
#pragma unroll
  for (int mt = 0; mt < 2; ++mt)
#pragma unroll
    for (int nt = 0; nt < 8; ++nt)
#pragma unroll
      for (int r = 0; r < 4; ++r)
        pp[((w * 2 + mt) * 16 + q * 4 + r) * 128 + nt * 16 + m16] = acc[mt][nt][r];
}

// -------------------------------------------------------------- reduce ----
__global__ void reduce_k(const float* __restrict__ part, const float* __restrict__ bout,
                         const float* __restrict__ accg, const float* __restrict__ bias,
                         const float* __restrict__ biasp, float* __restrict__ out) {
  int i = blockIdx.x * 256 + threadIdx.x;
  if (i < 131072) {
    float s = bout[i & 127];
#pragma unroll
    for (int ks = 0; ks < 16; ++ks) s += part[ks * 131072 + i];
    out[i] = s;
  } else if (i < 131080) {
    int tt = i - 131072;
    float base = (tt < 4) ? bias[0] : biasp[0];
    float x = base + accg[tt];
    out[i] = (x >= 0.f) ? x : 0.01f * x;   // leaky_relu, slope 0.01
  }
}

// -------------------------------------------------------------- launch ----
extern "C" void kernel_launch(void* const* d_in, const int* in_sizes, int n_in,
                              void* d_out, int out_size, void* d_ws, size_t ws_size,
                              hipStream_t stream) {
  const float* z      = (const float*)d_in[0];
  const int*   zmask  = (const int*)d_in[1];
  const float* pocket = (const float*)d_in[2];
  const float* cdis   = (const float*)d_in[3];
  const float* wlin   = (const float*)d_in[4];
  // d_in[5] = b_lin: cancels in softmax (constant shift per row) — unused.
  const float* wdis   = (const float*)d_in[6];
  const float* bdis   = (const float*)d_in[7];
  const float* wE     = (const float*)d_in[8];
  const float* bE     = (const float*)d_in[9];
  const float* wG     = (const float*)d_in[10];
  const float* bG     = (const float*)d_in[11];
  const float* bias   = (const float*)d_in[12];
  const float* wEp    = (const float*)d_in[13];
  const float* bEp    = (const float*)d_in[14];
  const float* wGp    = (const float*)d_in[15];
  const float* bGp    = (const float*)d_in[16];
  const float* biasp  = (const float*)d_in[17];
  const float* wout   = (const float*)d_in[18];
  const float* bout   = (const float*)d_in[19];

  char* ws = (char*)d_ws;
  float* accg           = (float*)(ws + 0);           // 8 floats
  unsigned short* wtlin = (unsigned short*)(ws + 1024);      // [32][128]
  unsigned short* pt    = (unsigned short*)(ws + 16384);     // [4][128][512]
  unsigned short* wto   = (unsigned short*)(ws + 1048576);   // [128][4096]
  unsigned short* lig   = (unsigned short*)(ws + 2097152);   // [1024][4096]
  float* part           = (float*)(ws + 10485760);           // [16][131072]
  float* outp = (float*)d_out;

  prep_k<<<1024, 256, 0, stream>>>(wlin, pocket, wout, wtlin, pt, wto, accg);
  mega_k<<<dim3(256, 4), 256, 57856, stream>>>(z, zmask, cdis, wdis, bdis,
      wE, bE, wG, bG, wEp, bEp, wGp, bGp, wtlin, pt, lig, accg);
  proj_k<<<dim3(8, 16), 256, 0, stream>>>(lig, wto, part);
  reduce_k<<<513, 256, 0, stream>>>(part, bout, accg, bias, biasp, outp);
}

// Round 3
// 471.035 us; speedup vs baseline: 1.0281x; 1.0281x over previous
//
#include <hip/hip_runtime.h>
#include <stdint.h>

// Problem constants: B=4, NP=512, NC=256, E=128, C=32, NBUCKET=20.

typedef float f32x4 __attribute__((ext_vector_type(4)));
typedef short s16x8 __attribute__((ext_vector_type(8)));

#define DEV static __device__ __forceinline__

DEV unsigned short f2bf(float f) {
  unsigned u = __builtin_bit_cast(unsigned, f);
  u += 0x7FFFu + ((u >> 16) & 1u);   // RNE
  return (unsigned short)(u >> 16);
}
DEV float bf2f(unsigned short h) {
  unsigned u = ((unsigned)h) << 16;
  return __builtin_bit_cast(float, u);
}

// ---------------------------------------------------------------- prep ----
// Segments (grid-stride over 1,970,184 items; zmb first => 64-aligned waves
// for ballot):
//  [0,524288)          zmb: packed z_mask[b][np][nc] -> bits zmb[(b,nc)][np]
//  [524288,1048576)    WTO[e][k] = W_out[k][e] bf16
//  [1048576,1310720)   PT[b][e][np] = pocket[b][np][e] bf16
//  [1310720,1314816)   WT_LIN[c][k] = W_lin[k][c] bf16
//  [1314816,1314824)   accg zero
//  [1314824,1839112)   cdisT[b][nc][np5*32+c] = cdis[b][16c+nc/16][16(nc&15)+np5]
//                      (524,288 items — R2 bug: was 131,072, b>0 poisoned)
//  [1839112,1970184)   out init = b_out broadcast
__global__ void prep_k(const float* __restrict__ wlin,
                       const float* __restrict__ pocket,
                       const float* __restrict__ wout,
                       const int* __restrict__ zmask,
                       const float* __restrict__ cdis,
                       const float* __restrict__ bout,
                       unsigned short* __restrict__ wtlin,
                       unsigned short* __restrict__ pt,
                       unsigned short* __restrict__ wto,
                       unsigned long long* __restrict__ zmb,
                       float* __restrict__ cdisT,
                       float* __restrict__ outp,
                       float* __restrict__ accg) {
  for (int i = blockIdx.x * 256 + threadIdx.x; i < 1970184; i += gridDim.x * 256) {
    if (i < 524288) {                 // zmb ballot: i = ((b*256+nc)*512)+np
      int np = i & 511, nc = (i >> 9) & 255, b = i >> 17;
      unsigned long long bal = __ballot(zmask[b * 131072 + np * 256 + nc] != 0);
      if ((i & 63) == 0) zmb[i >> 6] = bal;
    } else if (i < 1048576) {         // WTO
      int o = i - 524288;
      int e = o >> 12, k = o & 4095;
      wto[o] = f2bf(wout[k * 128 + e]);
    } else if (i < 1310720) {         // PT
      int o = i - 1048576;
      int np = o & 511, r = o >> 9;
      int e = r & 127, b = r >> 7;
      pt[o] = f2bf(pocket[(b * 512 + np) * 128 + e]);
    } else if (i < 1314816) {         // WT_LIN
      int o = i - 1310720;
      int k = o & 127, c = o >> 7;
      wtlin[o] = f2bf(wlin[k * 32 + c]);
    } else if (i < 1314824) {
      accg[i - 1314816] = 0.0f;
    } else if (i < 1839112) {         // cdisT: o = b*131072 + nc*512 + np5*32 + c
      int o = i - 1314824;
      int c = o & 31, np5 = (o >> 5) & 15, nc = (o >> 9) & 255, b = o >> 17;
      cdisT[o] = cdis[(b * 512 + 16 * c + (nc >> 4)) * 256 + 16 * (nc & 15) + np5];
    } else {                          // out bias init
      int o = i - 1839112;
      outp[o] = bout[o & 127];
    }
  }
}

// ---------------------------------------------------------------- mega ----
// One block per (nc, b). Phase 1 loads z MFMA A-fragments DIRECTLY from
// global (no LDS staging, no barriers): wave w owns np-tiles w*8..w*8+7.
// LDS: T bf16 [32][520] (33,280 B dynamic) + ~4.4 KB static => 4 blocks/CU.
extern __shared__ char smem[];

__global__ __launch_bounds__(256, 4) void mega_k(
    const float* __restrict__ z, const int* __restrict__ zmask,
    const float* __restrict__ cdisT,
    const float* __restrict__ wdis, const float* __restrict__ bdis_g,
    const float* __restrict__ wE, const float* __restrict__ bE,
    const float* __restrict__ wG, const float* __restrict__ bG,
    const float* __restrict__ wEp, const float* __restrict__ bEp,
    const float* __restrict__ wGp, const float* __restrict__ bGp,
    const unsigned short* __restrict__ wtlin,
    const unsigned short* __restrict__ pt,
    const unsigned long long* __restrict__ zmb,
    unsigned short* __restrict__ lig, float* __restrict__ accg) {
  const int nc = blockIdx.x, b = blockIdx.y;
  const int t = threadIdx.x;
  const int w = t >> 6, ln = t & 63;
  const int m16 = ln & 15, q = ln >> 4;

  unsigned short* T = (unsigned short*)smem;               // [32][520]

  __shared__ float s_wd[640];                              // W_dis [20][32]
  __shared__ float s_bd[32];
  __shared__ float s_we[32], s_wg[32], s_wep[32], s_wgp[32];
  __shared__ float s_red[160];                             // [32][5]
  __shared__ float s_gmax[32], s_gsum[32];
  __shared__ unsigned long long s_mb[4][8];                // scrambled mask bits
  __shared__ float s_r8[8];

  if (t < 32) {
    s_bd[t] = bdis_g[t];
    s_we[t] = wE[t]; s_wg[t] = wG[t];
    s_wep[t] = wEp[t]; s_wgp[t] = wGp[t];
  }
  for (int i = t; i < 640; i += 256) s_wd[i] = wdis[i];
  // mask_rep[b,c,nc,np] = z_mask[c&3][2nc+np/256][np&255] (contiguous per nc)
  for (int i = t; i < 2048; i += 256) {
    int cm = i >> 9, nn = i & 511;
    unsigned long long bal = __ballot(zmask[cm * 131072 + nc * 512 + nn] != 0);
    if ((i & 63) == 0) s_mb[cm][nn >> 6] = bal;
  }

  // ---- Phase 1: zc_pre = z @ W_lin, A-frags straight from global.
  f32x4 acc1[8][2];
#pragma unroll
  for (int i = 0; i < 8; ++i) {
    acc1[i][0] = f32x4{0.f, 0.f, 0.f, 0.f};
    acc1[i][1] = f32x4{0.f, 0.f, 0.f, 0.f};
  }
  const float* zb = z + (size_t)b * 16777216 + (size_t)nc * 128;
  for (int k0 = 0; k0 < 128; k0 += 32) {
    s16x8 bf0 = *(const s16x8*)(wtlin + m16 * 128 + k0 + q * 8);
    s16x8 bf1 = *(const s16x8*)(wtlin + (16 + m16) * 128 + k0 + q * 8);
#pragma unroll
    for (int bt = 0; bt < 4; ++bt) {
      f32x4 z0[2], z1[2];
#pragma unroll
      for (int i = 0; i < 2; ++i) {
        int np = (w * 8 + bt * 2 + i) * 16 + m16;
        const float* p = zb + (size_t)np * 32768 + k0 + q * 8;
        z0[i] = *(const f32x4*)p;
        z1[i] = *(const f32x4*)(p + 4);
      }
#pragma unroll
      for (int i = 0; i < 2; ++i) {
        s16x8 af;
        af[0] = (short)f2bf(z0[i][0]); af[1] = (short)f2bf(z0[i][1]);
        af[2] = (short)f2bf(z0[i][2]); af[3] = (short)f2bf(z0[i][3]);
        af[4] = (short)f2bf(z1[i][0]); af[5] = (short)f2bf(z1[i][1]);
        af[6] = (short)f2bf(z1[i][2]); af[7] = (short)f2bf(z1[i][3]);
        int ai = bt * 2 + i;
        acc1[ai][0] = __builtin_amdgcn_mfma_f32_16x16x32_bf16(af, bf0, acc1[ai][0], 0, 0, 0);
        acc1[ai][1] = __builtin_amdgcn_mfma_f32_16x16x32_bf16(af, bf1, acc1[ai][1], 0, 0, 0);
      }
    }
  }

  // ---- Phase 2: softmax over np per c. D-frag: col(c)=ln&15, row(np)=q*4+r.
  float mx[2] = {-3.0e38f, -3.0e38f};
#pragma unroll
  for (int ai = 0; ai < 8; ++ai)
#pragma unroll
    for (int ct = 0; ct < 2; ++ct)
#pragma unroll
      for (int r = 0; r < 4; ++r) mx[ct] = fmaxf(mx[ct], acc1[ai][ct][r]);
#pragma unroll
  for (int ct = 0; ct < 2; ++ct) {
    float v = mx[ct];
    v = fmaxf(v, __shfl_xor(v, 16));
    v = fmaxf(v, __shfl_xor(v, 32));
    mx[ct] = v;
  }
  if (ln < 16) { s_red[ln * 5 + w] = mx[0]; s_red[(16 + ln) * 5 + w] = mx[1]; }
  __syncthreads();
  if (t < 32)
    s_gmax[t] = fmaxf(fmaxf(s_red[t * 5], s_red[t * 5 + 1]),
                      fmaxf(s_red[t * 5 + 2], s_red[t * 5 + 3]));
  __syncthreads();
  float sm[2] = {0.f, 0.f};
#pragma unroll
  for (int ct = 0; ct < 2; ++ct) {
    float g = s_gmax[ct * 16 + m16];
#pragma unroll
    for (int ai = 0; ai < 8; ++ai)
#pragma unroll
      for (int r = 0; r < 4; ++r) {
        float e = __expf(acc1[ai][ct][r] - g);
        acc1[ai][ct][r] = e;
        sm[ct] += e;
      }
  }
#pragma unroll
  for (int ct = 0; ct < 2; ++ct) {
    float v = sm[ct];
    v += __shfl_xor(v, 16);
    v += __shfl_xor(v, 32);
    sm[ct] = v;
  }
  if (ln < 16) { s_red[ln * 5 + w] = sm[0]; s_red[(16 + ln) * 5 + w] = sm[1]; }
  __syncthreads();
  if (t < 32)
    s_gsum[t] = 1.0f / (s_red[t * 5] + s_red[t * 5 + 1] + s_red[t * 5 + 2] + s_red[t * 5 + 3]);
  __syncthreads();

  // ---- Phase 2b: scale + store T bf16 (packed 8B stores)
#pragma unroll
  for (int ct = 0; ct < 2; ++ct) {
    int c = ct * 16 + m16;
    float s = s_gsum[c];
#pragma unroll
    for (int ai = 0; ai < 8; ++ai) {
      int npb = (w * 8 + ai) * 16 + q * 4;
      unsigned lo = (unsigned)f2bf(acc1[ai][ct][0] * s) |
                    ((unsigned)f2bf(acc1[ai][ct][1] * s) << 16);
      unsigned hi = (unsigned)f2bf(acc1[ai][ct][2] * s) |
                    ((unsigned)f2bf(acc1[ai][ct][3] * s) << 16);
      *(uint2*)(T + c * 520 + npb) = make_uint2(lo, hi);
    }
  }
  __syncthreads();

  // ---- Phase 3: dis_bias (K=20 GEMM in registers) + mask, RMW into T.
  {
    const float SUSK = 8.4335794f;    // 1.14136 * e^2
    const float* cdb = cdisT + (size_t)(b * 256 + nc) * 512;
#pragma unroll
    for (int tt = 0; tt < 2; ++tt) {
      int task = t + tt * 256;
      int c = task & 31, np5 = task >> 5;
      float d = cdb[task];
      float val[32];
#pragma unroll
      for (int kk = 0; kk < 32; ++kk) val[kk] = s_bd[kk];
      for (int j = 0; j < 20; ++j) {
        float diff = d * (21.0f / 15.0f) - (float)(j + 1);
        float y1 = diff + 1.f, y2 = 1.f - diff;
        float u = 0.f;
        if (y1 > 0.f && y2 > 0.f) u = SUSK * __expf(-1.f / y1 - 1.f / y2);
#pragma unroll
        for (int kk = 0; kk < 32; ++kk) val[kk] += u * s_wd[j * 32 + kk];
      }
      int npb = np5 * 32;
      unsigned long long mw = s_mb[c & 3][npb >> 6];
#pragma unroll
      for (int kb2 = 0; kb2 < 4; ++kb2) {
        unsigned short* tp = T + c * 520 + npb + kb2 * 8;
        s16x8 tv = *(s16x8*)tp;
        s16x8 ov;
#pragma unroll
        for (int kk = 0; kk < 8; ++kk) {
          float x = bf2f((unsigned short)tv[kk]) + val[kb2 * 8 + kk];
          int mk = (int)((mw >> ((npb + kb2 * 8 + kk) & 63)) & 1ull);
          ov[kk] = (short)f2bf(mk ? 1e-9f : x);
        }
        *(s16x8*)tp = ov;
      }
    }
  }
  __syncthreads();

  // ---- Phase 4: gated energy heads; z_mask[b,np,nc] from packed zmb.
  {
    float aff = 0.f, prm = 0.f;
    const float bg0 = bG[0], be0 = bE[0], bgp0 = bGp[0], bep0 = bEp[0];
    const unsigned long long* zw = zmb + (size_t)(b * 256 + nc) * 8;
#pragma unroll
    for (int s = 0; s < 2; ++s) {
      int np = s * 256 + t;
      float g = bg0, e = be0, gp = bgp0, ep = bep0;
      for (int c = 0; c < 32; ++c) {
        float tv = bf2f(T[c * 520 + np]);
        g += tv * s_wg[c]; e += tv * s_we[c];
        gp += tv * s_wgp[c]; ep += tv * s_wep[c];
      }
      if ((zw[np >> 6] >> (np & 63)) & 1ull) {
        aff += e / (1.f + __expf(-g));
        prm += ep / (1.f + __expf(-gp));
      }
    }
#pragma unroll
    for (int d = 32; d >= 1; d >>= 1) {
      aff += __shfl_xor(aff, d);
      prm += __shfl_xor(prm, d);
    }
    if (ln == 0) { s_r8[w] = aff; s_r8[4 + w] = prm; }
    __syncthreads();
    if (t == 0) {
      atomicAdd(accg + b, s_r8[0] + s_r8[1] + s_r8[2] + s_r8[3]);
      atomicAdd(accg + 4 + b, s_r8[4] + s_r8[5] + s_r8[6] + s_r8[7]);
    }
  }

  // ---- Phase 5: lig[c,e] = sum_np T[c,np] * P[np,e] via MFMA.
  {
    f32x4 a5[2][2];
    a5[0][0] = f32x4{0.f, 0.f, 0.f, 0.f}; a5[0][1] = a5[0][0];
    a5[1][0] = a5[0][0]; a5[1][1] = a5[0][0];
    const unsigned short* ptb = pt + b * 65536;
    for (int k0 = 0; k0 < 512; k0 += 32) {
      s16x8 aT0 = *(const s16x8*)(T + m16 * 520 + k0 + q * 8);
      s16x8 aT1 = *(const s16x8*)(T + (16 + m16) * 520 + k0 + q * 8);
      s16x8 bP0 = *(const s16x8*)(ptb + (w * 32 + m16) * 512 + k0 + q * 8);
      s16x8 bP1 = *(const s16x8*)(ptb + (w * 32 + 16 + m16) * 512 + k0 + q * 8);
      a5[0][0] = __builtin_amdgcn_mfma_f32_16x16x32_bf16(aT0, bP0, a5[0][0], 0, 0, 0);
      a5[0][1] = __builtin_amdgcn_mfma_f32_16x16x32_bf16(aT0, bP1, a5[0][1], 0, 0, 0);
      a5[1][0] = __builtin_amdgcn_mfma_f32_16x16x32_bf16(aT1, bP0, a5[1][0], 0, 0, 0);
      a5[1][1] = __builtin_amdgcn_mfma_f32_16x16x32_bf16(aT1, bP1, a5[1][1], 0, 0, 0);
    }
    unsigned short* lg = lig + (size_t)(b * 256 + nc) * 4096;
#pragma unroll
    for (int mt = 0; mt < 2; ++mt)
#pragma unroll
      for (int u = 0; u < 2; ++u)
#pragma unroll
        for (int r = 0; r < 4; ++r) {
          int c = mt * 16 + q * 4 + r;
          int e = w * 32 + u * 16 + m16;
          lg[c * 128 + e] = f2bf(a5[mt][u][r]);
        }
  }
}

// ---------------------------------------------------------------- proj ----
// ligand = LIG[1024][4096] @ W_out^T-staged, split-K(16) -> atomicAdd into
// bias-pre-initialized out. Block (0,0) also finalizes affinity/prmsd.
__global__ __launch_bounds__(256, 2) void proj_k(
    const unsigned short* __restrict__ lig, const unsigned short* __restrict__ wto,
    const float* __restrict__ accg, const float* __restrict__ bias,
    const float* __restrict__ biasp, float* __restrict__ outp) {
  const int mb = blockIdx.x, ks = blockIdx.y;
  const int t = threadIdx.x, w = t >> 6, ln = t & 63;
  const int m16 = ln & 15, q = ln >> 4;
  f32x4 acc[2][8];
#pragma unroll
  for (int mt = 0; mt < 2; ++mt)
#pragma unroll
    for (int nt = 0; nt < 8; ++nt) acc[mt][nt] = f32x4{0.f, 0.f, 0.f, 0.f};
  const int kb = ks * 256;
  for (int k0 = 0; k0 < 256; k0 += 32) {
    s16x8 af[2], bf[8];
#pragma unroll
    for (int mt = 0; mt < 2; ++mt)
      af[mt] = *(const s16x8*)(lig + (size_t)(mb * 128 + (w * 2 + mt) * 16 + m16) * 4096 + kb + k0 + q * 8);
#pragma unroll
    for (int nt = 0; nt < 8; ++nt)
      bf[nt] = *(const s16x8*)(wto + (size_t)(nt * 16 + m16) * 4096 + kb + k0 + q * 8);
#pragma unroll
    for (int mt = 0; mt < 2; ++mt)
#pragma unroll
      for (int nt = 0; nt < 8; ++nt)
        acc[mt][nt] = __builtin_amdgcn_mfma_f32_16x16x32_bf16(af[mt], bf[nt], acc[mt][nt], 0, 0, 0);
  }
#pragma unroll
  for (int mt = 0; mt < 2; ++mt)
#pragma unroll
    for (int nt = 0; nt < 8; ++nt)
#pragma unroll
      for (int r = 0; r < 4; ++r)
        atomicAdd(outp + (size_t)(mb * 128 + (w * 2 + mt) * 16 + q * 4 + r) * 128 + nt * 16 + m16,
                  acc[mt][nt][r]);
  if (mb == 0 && ks == 0 && t < 8) {
    float base = (t < 4) ? bias[0] : biasp[0];
    float x = base + accg[t];
    outp[131072 + t] = (x >= 0.f) ? x : 0.01f * x;   // leaky_relu
  }
}

// -------------------------------------------------------------- launch ----
extern "C" void kernel_launch(void* const* d_in, const int* in_sizes, int n_in,
                              void* d_out, int out_size, void* d_ws, size_t ws_size,
                              hipStream_t stream) {
  const float* z      = (const float*)d_in[0];
  const int*   zmask  = (const int*)d_in[1];
  const float* pocket = (const float*)d_in[2];
  const float* cdis   = (const float*)d_in[3];
  const float* wlin   = (const float*)d_in[4];
  // d_in[5] = b_lin: cancels in softmax — unused.
  const float* wdis   = (const float*)d_in[6];
  const float* bdis   = (const float*)d_in[7];
  const float* wE     = (const float*)d_in[8];
  const float* bE     = (const float*)d_in[9];
  const float* wG     = (const float*)d_in[10];
  const float* bG     = (const float*)d_in[11];
  const float* bias   = (const float*)d_in[12];
  const float* wEp    = (const float*)d_in[13];
  const float* bEp    = (const float*)d_in[14];
  const float* wGp    = (const float*)d_in[15];
  const float* bGp    = (const float*)d_in[16];
  const float* biasp  = (const float*)d_in[17];
  const float* wout   = (const float*)d_in[18];
  const float* bout   = (const float*)d_in[19];

  char* ws = (char*)d_ws;
  float* accg                  = (float*)(ws + 0);              // 8 f
  unsigned short* wtlin        = (unsigned short*)(ws + 1024);  // 8 KB
  unsigned long long* zmb      = (unsigned long long*)(ws + 16384);   // 64 KB
  unsigned short* pt           = (unsigned short*)(ws + 131072);      // 512 KB
  float* cdisT                 = (float*)(ws + 655360);               // 2 MB
  unsigned short* wto          = (unsigned short*)(ws + 2752512);     // 1 MB
  unsigned short* lig          = (unsigned short*)(ws + 4194304);     // 8 MB
  float* outp = (float*)d_out;

  prep_k<<<1024, 256, 0, stream>>>(wlin, pocket, wout, zmask, cdis, bout,
                                   wtlin, pt, wto, zmb, cdisT, outp, accg);
  mega_k<<<dim3(256, 4), 256, 33280, stream>>>(z, zmask, cdisT, wdis, bdis,
      wE, bE, wG, bG, wEp, bEp, wGp, bGp, wtlin, pt, zmb, lig, accg);
  proj_k<<<dim3(8, 16), 256, 0, stream>>>(lig, wto, accg, bias, biasp, outp);
}